// Round 2
// baseline (288.303 us; speedup 1.0000x reference)
//
#include <hip/hip_runtime.h>
#include <math.h>

// Problem constants (from reference)
constexpr int B_ = 8;
constexpr int N_ = 8192;
constexpr int K_ = 48;
constexpr int NFREQ = 8;    // NUM_POS/2
constexpr int NEDGE = 16;
constexpr int FANIN = 23;   // NUM_POS + 7
constexpr float EPSF = 1e-12f;
constexpr int DRANGE = 2 * N_ - 1;  // 16383 possible d = j-n values, offset N_-1

// ---------------- helpers ----------------
struct F3 { float x, y, z; };
__device__ inline F3 f3(float a, float b, float c) { F3 r{a,b,c}; return r; }
__device__ inline F3 sub3(F3 a, F3 b) { return f3(a.x-b.x, a.y-b.y, a.z-b.z); }
__device__ inline F3 cross3(F3 a, F3 b) {
    return f3(a.y*b.z - a.z*b.y, a.z*b.x - a.x*b.z, a.x*b.y - a.y*b.x);
}
__device__ inline F3 norm3(F3 a) {
    float n = sqrtf(a.x*a.x + a.y*a.y + a.z*a.z);
    float inv = 1.0f / fmaxf(n, EPSF);
    return f3(a.x*inv, a.y*inv, a.z*inv);
}
__device__ inline float signf0(float x) {
    return (x > 0.0f) ? 1.0f : ((x < 0.0f) ? -1.0f : 0.0f);
}

// ---------------- kernel 1: positional-encoding table ----------------
// T[d + N-1][o] = bias[o] + sum_f sin(d*FR_f)*W[o][f] + cos(d*FR_f)*W[o][8+f]
__global__ void build_table(const float* __restrict__ tfrq, const float* __restrict__ ts,
                            const float* __restrict__ W, const float* __restrict__ bias,
                            float* __restrict__ T) {
    int idx = blockIdx.x * blockDim.x + threadIdx.x;
    if (idx >= DRANGE) return;
    float d = (float)(idx - (N_ - 1));
    float h[NEDGE];
    #pragma unroll
    for (int o = 0; o < NEDGE; o++) h[o] = bias[o];
    float tscale = ts[0];
    for (int f = 0; f < NFREQ; f++) {
        float s, c;
        sincosf(d * (tfrq[f] * tscale), &s, &c);
        #pragma unroll
        for (int o = 0; o < NEDGE; o++)
            h[o] = fmaf(s, W[o * FANIN + f], fmaf(c, W[o * FANIN + NFREQ + f], h[o]));
    }
    float4* Tp = (float4*)(T + (size_t)idx * 16);
    Tp[0] = make_float4(h[0], h[1], h[2], h[3]);
    Tp[1] = make_float4(h[4], h[5], h[6], h[7]);
    Tp[2] = make_float4(h[8], h[9], h[10], h[11]);
    Tp[3] = make_float4(h[12], h[13], h[14], h[15]);
}

// ---------------- kernel 2: per-node frame struct ----------------
// F[b][n] = 16 floats: [X.xyz,0][o1.xyz,0][n2.xyz,0][c.xyz,0]  (64B, gather-friendly)
__global__ void compute_F(const float* __restrict__ X, float* __restrict__ F) {
    int idx = blockIdx.x * blockDim.x + threadIdx.x;
    if (idx >= B_ * N_) return;
    int n = idx & (N_ - 1);
    const float* Xp = X + (size_t)idx * 3;
    float4 r0 = make_float4(Xp[0], Xp[1], Xp[2], 0.0f);
    float4 r1 = make_float4(0,0,0,0), r2 = r1, r3 = r1;
    if (n != 0 && n < N_ - 2) {
        F3 xm = f3(Xp[-3], Xp[-2], Xp[-1]);
        F3 x0 = f3(Xp[0], Xp[1], Xp[2]);
        F3 xp = f3(Xp[3], Xp[4], Xp[5]);
        F3 u2 = norm3(sub3(x0, xm));   // U[i-1]
        F3 u1 = norm3(sub3(xp, x0));   // U[i]
        F3 n2 = norm3(cross3(u2, u1));
        F3 o1 = norm3(sub3(u2, u1));
        F3 cc = cross3(o1, n2);
        r1 = make_float4(o1.x, o1.y, o1.z, 0.0f);
        r2 = make_float4(n2.x, n2.y, n2.z, 0.0f);
        r3 = make_float4(cc.x, cc.y, cc.z, 0.0f);
    }
    float4* Fp = (float4*)(F + (size_t)idx * 16);
    Fp[0] = r0; Fp[1] = r1; Fp[2] = r2; Fp[3] = r3;
}

// ---------------- kernels 3/5: edge pass (ssq-reduce or normalized-write) ----------------
// block: 256 threads = 256 consecutive n, fixed (b,k). grid = B*K*(N/256), k fastest, b slowest.
template<bool WRITE>
__launch_bounds__(256)
__global__ void edge_pass(const int* __restrict__ E, const float* __restrict__ F,
                          const float* __restrict__ T, const float* __restrict__ Wfull,
                          float* __restrict__ acc, float* __restrict__ out) {
    constexpr int NCH = N_ / 256;  // 32 chunks
    int bid = blockIdx.x;
    int k = bid % K_;
    int chunk = (bid / K_) % NCH;
    int b = bid / (K_ * NCH);
    int tid = threadIdx.x;
    int n = chunk * 256 + tid;

    __shared__ float sWq[NEDGE][8];   // W[:,16:23] padded to 8
    __shared__ float sR[NEDGE];
    __shared__ float sAcc[4][NEDGE];

    if (tid < NEDGE * 8) {
        int o = tid >> 3, f = tid & 7;
        sWq[o][f] = (f < 7) ? Wfull[o * FANIN + 16 + f] : 0.0f;
    }
    if constexpr (WRITE) {
        if (tid < NEDGE)
            sR[tid] = 1.0f / fmaxf(sqrtf(acc[((size_t)b * K_ + k) * NEDGE + tid]), EPSF);
    }
    __syncthreads();

    size_t node = (size_t)b * N_ + n;
    int j = E[node * K_ + k];
    size_t nodej = (size_t)b * N_ + j;

    // gathers: table row (64B) + own frame (64B, coalesced-ish) + neighbor frame (64B)
    const float4* tp = (const float4*)(T + (size_t)(j - n + (N_ - 1)) * 16);
    float4 t0 = tp[0], t1 = tp[1], t2 = tp[2], t3 = tp[3];
    const float4* fn = (const float4*)(F + node * 16);
    const float4* fj = (const float4*)(F + nodej * 16);
    float4 xn = fn[0], a1 = fn[1], a2 = fn[2], a3 = fn[3];  // X, o1, n2, c (rows of Of)
    float4 xj = fj[0], b1 = fj[1], b2 = fj[2], b3 = fj[3];

    // dU = l2norm(Of @ dX)
    float dX0 = xj.x - xn.x, dX1 = xj.y - xn.y, dX2 = xj.z - xn.z;
    float v0 = a1.x*dX0 + a1.y*dX1 + a1.z*dX2;
    float v1 = a2.x*dX0 + a2.y*dX1 + a2.z*dX2;
    float v2 = a3.x*dX0 + a3.y*dX1 + a3.z*dX2;
    float vinv = 1.0f / fmaxf(sqrtf(v0*v0 + v1*v1 + v2*v2), EPSF);
    float dU0 = v0*vinv, dU1 = v1*vinv, dU2 = v2*vinv;

    // R = Of^T * Oj : R[i][l] = a1[i]*b1[l] + a2[i]*b2[l] + a3[i]*b3[l]
    float R00 = a1.x*b1.x + a2.x*b2.x + a3.x*b3.x;
    float R11 = a1.y*b1.y + a2.y*b2.y + a3.y*b3.y;
    float R22 = a1.z*b1.z + a2.z*b2.z + a3.z*b3.z;
    float R21 = a1.z*b1.y + a2.z*b2.y + a3.z*b3.y;
    float R12 = a1.y*b1.z + a2.y*b2.z + a3.y*b3.z;
    float R02 = a1.x*b1.z + a2.x*b2.z + a3.x*b3.z;
    float R20 = a1.z*b1.x + a2.z*b2.x + a3.z*b3.x;
    float R10 = a1.y*b1.x + a2.y*b2.x + a3.y*b3.x;
    float R01 = a1.x*b1.y + a2.x*b2.y + a3.x*b3.y;

    float mg0 = 0.5f * sqrtf(fabsf(1.0f + R00 - R11 - R22) + EPSF);
    float mg1 = 0.5f * sqrtf(fabsf(1.0f - R00 + R11 - R22) + EPSF);
    float mg2 = 0.5f * sqrtf(fabsf(1.0f - R00 - R11 + R22) + EPSF);
    float qx = signf0(R21 - R12) * mg0;
    float qy = signf0(R02 - R20) * mg1;
    float qz = signf0(R10 - R01) * mg2;
    float qw = 0.5f * sqrtf(fmaxf(1.0f + R00 + R11 + R22, 0.0f) + EPSF);
    float qinv = 1.0f / fmaxf(sqrtf(qx*qx + qy*qy + qz*qz + qw*qw), EPSF);
    qx *= qinv; qy *= qinv; qz *= qinv; qw *= qinv;

    float q[7] = {dU0, dU1, dU2, qx, qy, qz, qw};
    float tv[16] = {t0.x,t0.y,t0.z,t0.w, t1.x,t1.y,t1.z,t1.w,
                    t2.x,t2.y,t2.z,t2.w, t3.x,t3.y,t3.z,t3.w};

    // h[o] = T[d][o] + W[o,16:23] . q
    float h[NEDGE];
    #pragma unroll
    for (int o = 0; o < NEDGE; o++) {
        float a = tv[o];
        #pragma unroll
        for (int f = 0; f < 7; f++) a = fmaf(q[f], sWq[o][f], a);
        h[o] = a;
    }

    if constexpr (WRITE) {
        size_t base = (node * K_ + k) * 16;
        float4* op = (float4*)(out + base);
        op[0] = make_float4(h[0]*sR[0],  h[1]*sR[1],  h[2]*sR[2],  h[3]*sR[3]);
        op[1] = make_float4(h[4]*sR[4],  h[5]*sR[5],  h[6]*sR[6],  h[7]*sR[7]);
        op[2] = make_float4(h[8]*sR[8],  h[9]*sR[9],  h[10]*sR[10], h[11]*sR[11]);
        op[3] = make_float4(h[12]*sR[12], h[13]*sR[13], h[14]*sR[14], h[15]*sR[15]);
    } else {
        int lane = tid & 63, wid = tid >> 6;
        #pragma unroll
        for (int o = 0; o < NEDGE; o++) {
            float vsq = h[o] * h[o];
            #pragma unroll
            for (int m = 1; m < 64; m <<= 1) vsq += __shfl_xor(vsq, m, 64);
            if (lane == 0) sAcc[wid][o] = vsq;
        }
        __syncthreads();
        if (tid < NEDGE) {
            float t = sAcc[0][tid] + sAcc[1][tid] + sAcc[2][tid] + sAcc[3][tid];
            atomicAdd(&acc[((size_t)b * K_ + k) * NEDGE + tid], t);
        }
    }
}

// ---------------- launch ----------------
extern "C" void kernel_launch(void* const* d_in, const int* in_sizes, int n_in,
                              void* d_out, int out_size, void* d_ws, size_t ws_size,
                              hipStream_t stream) {
    const float* X    = (const float*)d_in[0];   // p (B,N,3)
    const int*   E    = (const int*)d_in[1];     // e_idx (B,N,K)
    // d_in[2] = mask (unused by reference)
    const float* tfrq = (const float*)d_in[3];   // (8,)
    const float* ts   = (const float*)d_in[4];   // scalar
    const float* W    = (const float*)d_in[5];   // (16,23)
    const float* bias = (const float*)d_in[6];   // (16,)
    float* out = (float*)d_out;

    float* F   = (float*)d_ws;                         // B*N*16 floats = 4.19 MB
    float* T   = F + (size_t)B_ * N_ * 16;             // DRANGE*16 = 1.05 MB
    float* acc = T + (size_t)DRANGE * 16;              // B*K*16 = 6144 floats

    hipMemsetAsync(acc, 0, (size_t)B_ * K_ * NEDGE * sizeof(float), stream);

    build_table<<<(DRANGE + 255) / 256, 256, 0, stream>>>(tfrq, ts, W, bias, T);
    compute_F<<<(B_ * N_ + 255) / 256, 256, 0, stream>>>(X, F);

    int grid = B_ * K_ * (N_ / 256);
    edge_pass<false><<<grid, 256, 0, stream>>>(E, F, T, W, acc, out);
    edge_pass<true><<<grid, 256, 0, stream>>>(E, F, T, W, acc, out);
}

// Round 3
// 241.612 us; speedup vs baseline: 1.1932x; 1.1932x over previous
//
#include <hip/hip_runtime.h>
#include <math.h>

// Problem constants (from reference)
constexpr int B_ = 8;
constexpr int N_ = 8192;
constexpr int K_ = 48;
constexpr int NFREQ = 8;    // NUM_POS/2
constexpr int NEDGE = 16;
constexpr int FANIN = 23;   // NUM_POS + 7
constexpr float EPSF = 1e-12f;
constexpr int DRANGE = 2 * N_ - 1;  // 16383 possible d = j-n values, offset N_-1

// ---------------- helpers ----------------
struct F3 { float x, y, z; };
__device__ inline F3 f3(float a, float b, float c) { F3 r{a,b,c}; return r; }
__device__ inline F3 sub3(F3 a, F3 b) { return f3(a.x-b.x, a.y-b.y, a.z-b.z); }
__device__ inline F3 cross3(F3 a, F3 b) {
    return f3(a.y*b.z - a.z*b.y, a.z*b.x - a.x*b.z, a.x*b.y - a.y*b.x);
}
__device__ inline F3 norm3(F3 a) {
    float n = sqrtf(a.x*a.x + a.y*a.y + a.z*a.z);
    float inv = 1.0f / fmaxf(n, EPSF);
    return f3(a.x*inv, a.y*inv, a.z*inv);
}
__device__ inline float signf0(float x) {
    return (x > 0.0f) ? 1.0f : ((x < 0.0f) ? -1.0f : 0.0f);
}

// ---------------- kernel 1: positional-encoding table ----------------
// T[d + N-1][o] = bias[o] + sum_f sin(d*FR_f)*W[o][f] + cos(d*FR_f)*W[o][8+f]
__global__ void build_table(const float* __restrict__ tfrq, const float* __restrict__ ts,
                            const float* __restrict__ W, const float* __restrict__ bias,
                            float* __restrict__ T) {
    int idx = blockIdx.x * blockDim.x + threadIdx.x;
    if (idx >= DRANGE) return;
    float d = (float)(idx - (N_ - 1));
    float h[NEDGE];
    #pragma unroll
    for (int o = 0; o < NEDGE; o++) h[o] = bias[o];
    float tscale = ts[0];
    for (int f = 0; f < NFREQ; f++) {
        float s, c;
        sincosf(d * (tfrq[f] * tscale), &s, &c);
        #pragma unroll
        for (int o = 0; o < NEDGE; o++)
            h[o] = fmaf(s, W[o * FANIN + f], fmaf(c, W[o * FANIN + NFREQ + f], h[o]));
    }
    float4* Tp = (float4*)(T + (size_t)idx * 16);
    Tp[0] = make_float4(h[0], h[1], h[2], h[3]);
    Tp[1] = make_float4(h[4], h[5], h[6], h[7]);
    Tp[2] = make_float4(h[8], h[9], h[10], h[11]);
    Tp[3] = make_float4(h[12], h[13], h[14], h[15]);
}

// ---------------- kernel 2: per-node frame struct ----------------
// F[b][n] = 16 floats: [X.xyz,0][o1.xyz,0][n2.xyz,0][c.xyz,0]  (64B, gather-friendly)
__global__ void compute_F(const float* __restrict__ X, float* __restrict__ F) {
    int idx = blockIdx.x * blockDim.x + threadIdx.x;
    if (idx >= B_ * N_) return;
    int n = idx & (N_ - 1);
    const float* Xp = X + (size_t)idx * 3;
    float4 r0 = make_float4(Xp[0], Xp[1], Xp[2], 0.0f);
    float4 r1 = make_float4(0,0,0,0), r2 = r1, r3 = r1;
    if (n != 0 && n < N_ - 2) {
        F3 xm = f3(Xp[-3], Xp[-2], Xp[-1]);
        F3 x0 = f3(Xp[0], Xp[1], Xp[2]);
        F3 xp = f3(Xp[3], Xp[4], Xp[5]);
        F3 u2 = norm3(sub3(x0, xm));   // U[i-1]
        F3 u1 = norm3(sub3(xp, x0));   // U[i]
        F3 n2 = norm3(cross3(u2, u1));
        F3 o1 = norm3(sub3(u2, u1));
        F3 cc = cross3(o1, n2);
        r1 = make_float4(o1.x, o1.y, o1.z, 0.0f);
        r2 = make_float4(n2.x, n2.y, n2.z, 0.0f);
        r3 = make_float4(cc.x, cc.y, cc.z, 0.0f);
    }
    float4* Fp = (float4*)(F + (size_t)idx * 16);
    Fp[0] = r0; Fp[1] = r1; Fp[2] = r2; Fp[3] = r3;
}

// ---------------- core per-edge computation ----------------
__device__ inline void edge_h(const float* __restrict__ F, const float* __restrict__ T,
                              const float (*sWq)[8], size_t bbase, int n, int j,
                              float* __restrict__ h) {
    const float4* tp = (const float4*)(T + (size_t)(j - n + (N_ - 1)) * 16);
    float4 t0 = tp[0], t1 = tp[1], t2 = tp[2], t3 = tp[3];
    const float4* fn = (const float4*)(F + (bbase + n) * 16);
    const float4* fj = (const float4*)(F + (bbase + j) * 16);
    float4 xn = fn[0], a1 = fn[1], a2 = fn[2], a3 = fn[3];  // X, o1, n2, c (rows of Of)
    float4 xj = fj[0], b1 = fj[1], b2 = fj[2], b3 = fj[3];

    // dU = l2norm(Of @ dX)
    float dX0 = xj.x - xn.x, dX1 = xj.y - xn.y, dX2 = xj.z - xn.z;
    float v0 = a1.x*dX0 + a1.y*dX1 + a1.z*dX2;
    float v1 = a2.x*dX0 + a2.y*dX1 + a2.z*dX2;
    float v2 = a3.x*dX0 + a3.y*dX1 + a3.z*dX2;
    float vinv = 1.0f / fmaxf(sqrtf(v0*v0 + v1*v1 + v2*v2), EPSF);
    float dU0 = v0*vinv, dU1 = v1*vinv, dU2 = v2*vinv;

    // R = Of^T * Oj : R[i][l] = a1[i]*b1[l] + a2[i]*b2[l] + a3[i]*b3[l]
    float R00 = a1.x*b1.x + a2.x*b2.x + a3.x*b3.x;
    float R11 = a1.y*b1.y + a2.y*b2.y + a3.y*b3.y;
    float R22 = a1.z*b1.z + a2.z*b2.z + a3.z*b3.z;
    float R21 = a1.z*b1.y + a2.z*b2.y + a3.z*b3.y;
    float R12 = a1.y*b1.z + a2.y*b2.z + a3.y*b3.z;
    float R02 = a1.x*b1.z + a2.x*b2.z + a3.x*b3.z;
    float R20 = a1.z*b1.x + a2.z*b2.x + a3.z*b3.x;
    float R10 = a1.y*b1.x + a2.y*b2.x + a3.y*b3.x;
    float R01 = a1.x*b1.y + a2.x*b2.y + a3.x*b3.y;

    float mg0 = 0.5f * sqrtf(fabsf(1.0f + R00 - R11 - R22) + EPSF);
    float mg1 = 0.5f * sqrtf(fabsf(1.0f - R00 + R11 - R22) + EPSF);
    float mg2 = 0.5f * sqrtf(fabsf(1.0f - R00 - R11 + R22) + EPSF);
    float qx = signf0(R21 - R12) * mg0;
    float qy = signf0(R02 - R20) * mg1;
    float qz = signf0(R10 - R01) * mg2;
    float qw = 0.5f * sqrtf(fmaxf(1.0f + R00 + R11 + R22, 0.0f) + EPSF);
    float qinv = 1.0f / fmaxf(sqrtf(qx*qx + qy*qy + qz*qz + qw*qw), EPSF);
    qx *= qinv; qy *= qinv; qz *= qinv; qw *= qinv;

    float q[7] = {dU0, dU1, dU2, qx, qy, qz, qw};
    float tv[16] = {t0.x,t0.y,t0.z,t0.w, t1.x,t1.y,t1.z,t1.w,
                    t2.x,t2.y,t2.z,t2.w, t3.x,t3.y,t3.z,t3.w};

    #pragma unroll
    for (int o = 0; o < NEDGE; o++) {
        float a = tv[o];
        #pragma unroll
        for (int f = 0; f < 7; f++) a = fmaf(q[f], sWq[o][f], a);
        h[o] = a;
    }
}

// ---------------- pass A: sum-of-squares reduce ----------------
// XCD-pinned: b = bid & 7 (8 batches <-> 8 XCDs, hardware round-robin).
// Each thread handles EPT=4 edges (same b,k; n = base + tid + 256*e).
__launch_bounds__(256)
__global__ void ssq_pass(const int* __restrict__ E, const float* __restrict__ F,
                         const float* __restrict__ T, const float* __restrict__ Wfull,
                         float* __restrict__ acc) {
    constexpr int EPT = 4;
    constexpr int NCH = N_ / (256 * EPT);  // 8 chunks
    int bid = blockIdx.x;
    int b = bid & 7;
    int r = bid >> 3;
    int k = r % K_;
    int chunk = r / K_;
    int tid = threadIdx.x;
    int nbase = chunk * 256 * EPT + tid;

    __shared__ float sWq[NEDGE][8];
    __shared__ float sAcc[4][NEDGE];

    if (tid < NEDGE * 8) {
        int o = tid >> 3, f = tid & 7;
        sWq[o][f] = (f < 7) ? Wfull[o * FANIN + 16 + f] : 0.0f;
    }
    __syncthreads();

    size_t bbase = (size_t)b * N_;
    float vsq[NEDGE];
    #pragma unroll
    for (int o = 0; o < NEDGE; o++) vsq[o] = 0.0f;

    int js[EPT];
    #pragma unroll
    for (int e = 0; e < EPT; e++)
        js[e] = E[(bbase + nbase + 256 * e) * K_ + k];

    #pragma unroll
    for (int e = 0; e < EPT; e++) {
        float h[NEDGE];
        edge_h(F, T, sWq, bbase, nbase + 256 * e, js[e], h);
        #pragma unroll
        for (int o = 0; o < NEDGE; o++) vsq[o] = fmaf(h[o], h[o], vsq[o]);
    }

    int lane = tid & 63, wid = tid >> 6;
    #pragma unroll
    for (int o = 0; o < NEDGE; o++) {
        float v = vsq[o];
        #pragma unroll
        for (int m = 1; m < 64; m <<= 1) v += __shfl_xor(v, m, 64);
        if (lane == 0) sAcc[wid][o] = v;
    }
    __syncthreads();
    if (tid < NEDGE) {
        float t = sAcc[0][tid] + sAcc[1][tid] + sAcc[2][tid] + sAcc[3][tid];
        atomicAdd(&acc[((size_t)b * K_ + k) * NEDGE + tid], t);
    }
}

// ---------------- pass B: recompute + normalized write ----------------
__launch_bounds__(256)
__global__ void write_pass(const int* __restrict__ E, const float* __restrict__ F,
                           const float* __restrict__ T, const float* __restrict__ Wfull,
                           const float* __restrict__ acc, float* __restrict__ out) {
    constexpr int NCH = N_ / 256;  // 32 chunks
    int bid = blockIdx.x;
    int b = bid & 7;
    int r = bid >> 3;
    int k = r % K_;
    int chunk = r / K_;
    int tid = threadIdx.x;
    int n = chunk * 256 + tid;

    __shared__ float sWq[NEDGE][8];
    __shared__ float sR[NEDGE];

    if (tid < NEDGE * 8) {
        int o = tid >> 3, f = tid & 7;
        sWq[o][f] = (f < 7) ? Wfull[o * FANIN + 16 + f] : 0.0f;
    }
    if (tid < NEDGE)
        sR[tid] = 1.0f / fmaxf(sqrtf(acc[((size_t)b * K_ + k) * NEDGE + tid]), EPSF);
    __syncthreads();

    size_t bbase = (size_t)b * N_;
    int j = E[(bbase + n) * K_ + k];

    float h[NEDGE];
    edge_h(F, T, sWq, bbase, n, j, h);

    size_t base = ((bbase + n) * K_ + k) * 16;
    float4* op = (float4*)(out + base);
    op[0] = make_float4(h[0]*sR[0],   h[1]*sR[1],   h[2]*sR[2],   h[3]*sR[3]);
    op[1] = make_float4(h[4]*sR[4],   h[5]*sR[5],   h[6]*sR[6],   h[7]*sR[7]);
    op[2] = make_float4(h[8]*sR[8],   h[9]*sR[9],   h[10]*sR[10], h[11]*sR[11]);
    op[3] = make_float4(h[12]*sR[12], h[13]*sR[13], h[14]*sR[14], h[15]*sR[15]);
}

// ---------------- launch ----------------
extern "C" void kernel_launch(void* const* d_in, const int* in_sizes, int n_in,
                              void* d_out, int out_size, void* d_ws, size_t ws_size,
                              hipStream_t stream) {
    const float* X    = (const float*)d_in[0];   // p (B,N,3)
    const int*   E    = (const int*)d_in[1];     // e_idx (B,N,K)
    // d_in[2] = mask (unused by reference)
    const float* tfrq = (const float*)d_in[3];   // (8,)
    const float* ts   = (const float*)d_in[4];   // scalar
    const float* W    = (const float*)d_in[5];   // (16,23)
    const float* bias = (const float*)d_in[6];   // (16,)
    float* out = (float*)d_out;

    float* F   = (float*)d_ws;                         // B*N*16 floats = 4.19 MB
    float* T   = F + (size_t)B_ * N_ * 16;             // DRANGE*16 = 1.05 MB
    float* acc = T + (size_t)DRANGE * 16;              // B*K*16 = 6144 floats

    hipMemsetAsync(acc, 0, (size_t)B_ * K_ * NEDGE * sizeof(float), stream);

    build_table<<<(DRANGE + 255) / 256, 256, 0, stream>>>(tfrq, ts, W, bias, T);
    compute_F<<<(B_ * N_ + 255) / 256, 256, 0, stream>>>(X, F);

    int gridA = 8 * K_ * (N_ / 1024);   // b in low 3 bits
    ssq_pass<<<gridA, 256, 0, stream>>>(E, F, T, W, acc);

    int gridB = 8 * K_ * (N_ / 256);    // b in low 3 bits
    write_pass<<<gridB, 256, 0, stream>>>(E, F, T, W, acc, out);
}

// Round 4
// 204.831 us; speedup vs baseline: 1.4075x; 1.1796x over previous
//
#include <hip/hip_runtime.h>
#include <math.h>

// Problem constants (from reference)
constexpr int B_ = 8;
constexpr int N_ = 8192;
constexpr int K_ = 48;
constexpr int NFREQ = 8;    // NUM_POS/2
constexpr int NEDGE = 16;
constexpr int FANIN = 23;   // NUM_POS + 7
constexpr float EPSF = 1e-12f;
constexpr int DRANGE = 2 * N_ - 1;  // 16383 possible d = j-n values, offset N_-1

// ---------------- helpers ----------------
struct F3 { float x, y, z; };
__device__ inline F3 f3(float a, float b, float c) { F3 r{a,b,c}; return r; }
__device__ inline F3 sub3(F3 a, F3 b) { return f3(a.x-b.x, a.y-b.y, a.z-b.z); }
__device__ inline F3 cross3(F3 a, F3 b) {
    return f3(a.y*b.z - a.z*b.y, a.z*b.x - a.x*b.z, a.x*b.y - a.y*b.x);
}
__device__ inline F3 norm3(F3 a) {
    float n = sqrtf(a.x*a.x + a.y*a.y + a.z*a.z);
    float inv = 1.0f / fmaxf(n, EPSF);
    return f3(a.x*inv, a.y*inv, a.z*inv);
}
__device__ inline float signf0(float x) {
    return (x > 0.0f) ? 1.0f : ((x < 0.0f) ? -1.0f : 0.0f);
}
__device__ inline unsigned int bf16rne(float x) {
    unsigned int u = __float_as_uint(x);
    return (u + 0x7fffu + ((u >> 16) & 1u)) >> 16;
}
// unpack 8 bf16 (one uint4) -> 8 floats
__device__ inline void unpack8(uint4 v, float* f) {
    f[0] = __uint_as_float(v.x << 16); f[1] = __uint_as_float(v.x & 0xffff0000u);
    f[2] = __uint_as_float(v.y << 16); f[3] = __uint_as_float(v.y & 0xffff0000u);
    f[4] = __uint_as_float(v.z << 16); f[5] = __uint_as_float(v.z & 0xffff0000u);
    f[6] = __uint_as_float(v.w << 16); f[7] = __uint_as_float(v.w & 0xffff0000u);
}

// ---------------- kernel 1: positional-encoding table (bf16, 32B rows) ----------------
__global__ void build_table(const float* __restrict__ tfrq, const float* __restrict__ ts,
                            const float* __restrict__ W, const float* __restrict__ bias,
                            unsigned short* __restrict__ T) {
    int idx = blockIdx.x * blockDim.x + threadIdx.x;
    if (idx >= DRANGE) return;
    float d = (float)(idx - (N_ - 1));
    float h[NEDGE];
    #pragma unroll
    for (int o = 0; o < NEDGE; o++) h[o] = bias[o];
    float tscale = ts[0];
    for (int f = 0; f < NFREQ; f++) {
        float s, c;
        sincosf(d * (tfrq[f] * tscale), &s, &c);
        #pragma unroll
        for (int o = 0; o < NEDGE; o++)
            h[o] = fmaf(s, W[o * FANIN + f], fmaf(c, W[o * FANIN + NFREQ + f], h[o]));
    }
    uint4 r0, r1;
    r0.x = bf16rne(h[0])  | (bf16rne(h[1])  << 16);
    r0.y = bf16rne(h[2])  | (bf16rne(h[3])  << 16);
    r0.z = bf16rne(h[4])  | (bf16rne(h[5])  << 16);
    r0.w = bf16rne(h[6])  | (bf16rne(h[7])  << 16);
    r1.x = bf16rne(h[8])  | (bf16rne(h[9])  << 16);
    r1.y = bf16rne(h[10]) | (bf16rne(h[11]) << 16);
    r1.z = bf16rne(h[12]) | (bf16rne(h[13]) << 16);
    r1.w = bf16rne(h[14]) | (bf16rne(h[15]) << 16);
    uint4* Tp = (uint4*)(T + (size_t)idx * 16);
    Tp[0] = r0; Tp[1] = r1;
}

// ---------------- kernel 2: per-node frame (12 floats, 48B rows) ----------------
// layout: [X.xyz, o1.xyz, n2.xyz, c.xyz]
__global__ void compute_F(const float* __restrict__ X, float* __restrict__ F) {
    int idx = blockIdx.x * blockDim.x + threadIdx.x;
    if (idx >= B_ * N_) return;
    int n = idx & (N_ - 1);
    const float* Xp = X + (size_t)idx * 3;
    float o[12];
    o[0] = Xp[0]; o[1] = Xp[1]; o[2] = Xp[2];
    #pragma unroll
    for (int i = 3; i < 12; i++) o[i] = 0.0f;
    if (n != 0 && n < N_ - 2) {
        F3 xm = f3(Xp[-3], Xp[-2], Xp[-1]);
        F3 x0 = f3(Xp[0], Xp[1], Xp[2]);
        F3 xp = f3(Xp[3], Xp[4], Xp[5]);
        F3 u2 = norm3(sub3(x0, xm));
        F3 u1 = norm3(sub3(xp, x0));
        F3 n2 = norm3(cross3(u2, u1));
        F3 o1 = norm3(sub3(u2, u1));
        F3 cc = cross3(o1, n2);
        o[3] = o1.x; o[4] = o1.y; o[5] = o1.z;
        o[6] = n2.x; o[7] = n2.y; o[8] = n2.z;
        o[9] = cc.x; o[10] = cc.y; o[11] = cc.z;
    }
    float4* Fp = (float4*)(F + (size_t)idx * 12);
    Fp[0] = make_float4(o[0], o[1], o[2], o[3]);
    Fp[1] = make_float4(o[4], o[5], o[6], o[7]);
    Fp[2] = make_float4(o[8], o[9], o[10], o[11]);
}

// ---------------- core per-edge computation ----------------
// fn frame passed in regs (a0,a1,a2); fj gathered; T row gathered (bf16).
__device__ inline void compute_edge(float4 a0, float4 a1, float4 a2,
                                    const float* __restrict__ F,
                                    const unsigned short* __restrict__ T,
                                    const float (*sWq)[8],
                                    size_t bbase, int n, int j,
                                    float* __restrict__ h) {
    const float4* fjp = (const float4*)(F + (bbase + (size_t)j) * 12);
    float4 b0 = fjp[0], b1 = fjp[1], b2 = fjp[2];
    const uint4* tp = (const uint4*)(T + (size_t)(j - n + (N_ - 1)) * 16);
    uint4 t0 = tp[0], t1 = tp[1];
    float tv[16];
    unpack8(t0, tv);
    unpack8(t1, tv + 8);

    // fn: X=(a0.x,a0.y,a0.z) o1=(a0.w,a1.x,a1.y) n2=(a1.z,a1.w,a2.x) c=(a2.y,a2.z,a2.w)
    float A1x = a0.w, A1y = a1.x, A1z = a1.y;
    float A2x = a1.z, A2y = a1.w, A2z = a2.x;
    float A3x = a2.y, A3y = a2.z, A3z = a2.w;
    float B1x = b0.w, B1y = b1.x, B1z = b1.y;
    float B2x = b1.z, B2y = b1.w, B2z = b2.x;
    float B3x = b2.y, B3y = b2.z, B3z = b2.w;

    // dU = l2norm(Of @ dX): rows of Of are A1,A2,A3
    float dX0 = b0.x - a0.x, dX1 = b0.y - a0.y, dX2 = b0.z - a0.z;
    float v0 = A1x*dX0 + A1y*dX1 + A1z*dX2;
    float v1 = A2x*dX0 + A2y*dX1 + A2z*dX2;
    float v2 = A3x*dX0 + A3y*dX1 + A3z*dX2;
    float vinv = 1.0f / fmaxf(sqrtf(v0*v0 + v1*v1 + v2*v2), EPSF);
    float dU0 = v0*vinv, dU1 = v1*vinv, dU2 = v2*vinv;

    // R[i][l] = A1[i]B1[l] + A2[i]B2[l] + A3[i]B3[l]
    float R00 = A1x*B1x + A2x*B2x + A3x*B3x;
    float R11 = A1y*B1y + A2y*B2y + A3y*B3y;
    float R22 = A1z*B1z + A2z*B2z + A3z*B3z;
    float R21 = A1z*B1y + A2z*B2y + A3z*B3y;
    float R12 = A1y*B1z + A2y*B2z + A3y*B3z;
    float R02 = A1x*B1z + A2x*B2z + A3x*B3z;
    float R20 = A1z*B1x + A2z*B2x + A3z*B3x;
    float R10 = A1y*B1x + A2y*B2x + A3y*B3x;
    float R01 = A1x*B1y + A2x*B2y + A3x*B3y;

    float mg0 = 0.5f * sqrtf(fabsf(1.0f + R00 - R11 - R22) + EPSF);
    float mg1 = 0.5f * sqrtf(fabsf(1.0f - R00 + R11 - R22) + EPSF);
    float mg2 = 0.5f * sqrtf(fabsf(1.0f - R00 - R11 + R22) + EPSF);
    float qx = signf0(R21 - R12) * mg0;
    float qy = signf0(R02 - R20) * mg1;
    float qz = signf0(R10 - R01) * mg2;
    float qw = 0.5f * sqrtf(fmaxf(1.0f + R00 + R11 + R22, 0.0f) + EPSF);
    float qinv = 1.0f / fmaxf(sqrtf(qx*qx + qy*qy + qz*qz + qw*qw), EPSF);
    qx *= qinv; qy *= qinv; qz *= qinv; qw *= qinv;

    float q[7] = {dU0, dU1, dU2, qx, qy, qz, qw};
    #pragma unroll
    for (int o = 0; o < NEDGE; o++) {
        float a = tv[o];
        #pragma unroll
        for (int f = 0; f < 7; f++) a = fmaf(q[f], sWq[o][f], a);
        h[o] = a;
    }
}

// ---------------- pass A: sum-of-squares reduce ----------------
// block = (b, kq, n-chunk of 256). thread owns n, loops 12 k (fn amortized).
__launch_bounds__(256)
__global__ void ssq_pass(const int* __restrict__ E, const float* __restrict__ F,
                         const unsigned short* __restrict__ T, const float* __restrict__ Wfull,
                         float* __restrict__ acc) {
    int bid = blockIdx.x;
    int b = bid & 7;
    int r = bid >> 3;
    int kq = r & 3;            // which 12-k group
    int chunk = r >> 2;        // 0..31
    int tid = threadIdx.x;
    int n = chunk * 256 + tid;
    int lane = tid & 63, wid = tid >> 6;

    __shared__ float sWq[NEDGE][8];
    __shared__ float sPart[4][12][NEDGE];

    if (tid < NEDGE * 8) {
        int o = tid >> 3, f = tid & 7;
        sWq[o][f] = (f < 7) ? Wfull[o * FANIN + 16 + f] : 0.0f;
    }
    __syncthreads();

    size_t bbase = (size_t)b * N_;
    size_t node = bbase + n;

    const float4* fnp = (const float4*)(F + node * 12);
    float4 a0 = fnp[0], a1 = fnp[1], a2 = fnp[2];

    const int4* ep = (const int4*)(E + node * K_ + kq * 12);
    int4 e0 = ep[0], e1 = ep[1], e2 = ep[2];
    int js[12] = {e0.x, e0.y, e0.z, e0.w, e1.x, e1.y, e1.z, e1.w, e2.x, e2.y, e2.z, e2.w};

    #pragma unroll 2
    for (int kk = 0; kk < 12; kk++) {
        float h[NEDGE];
        compute_edge(a0, a1, a2, F, T, sWq, bbase, n, js[kk], h);
        #pragma unroll
        for (int o = 0; o < NEDGE; o++) {
            float v = h[o] * h[o];
            #pragma unroll
            for (int m = 1; m < 64; m <<= 1) v += __shfl_xor(v, m, 64);
            if (lane == 0) sPart[wid][kk][o] = v;
        }
    }
    __syncthreads();
    if (tid < 12 * NEDGE) {
        int kk = tid >> 4, o = tid & 15;
        float t = sPart[0][kk][o] + sPart[1][kk][o] + sPart[2][kk][o] + sPart[3][kk][o];
        atomicAdd(&acc[((size_t)b * K_ + kq * 12 + kk) * NEDGE + o], t);
    }
}

// ---------------- kernel: reciprocal norms ----------------
__global__ void inv_kernel(const float* __restrict__ acc, float* __restrict__ rinv) {
    int i = blockIdx.x * blockDim.x + threadIdx.x;
    if (i >= B_ * K_ * NEDGE) return;
    rinv[i] = 1.0f / fmaxf(sqrtf(acc[i]), EPSF);
}

// ---------------- pass B: recompute + normalized write (k-major lanes) ----------------
__launch_bounds__(256)
__global__ void write_pass(const int* __restrict__ E, const float* __restrict__ F,
                           const unsigned short* __restrict__ T, const float* __restrict__ Wfull,
                           const float* __restrict__ rinv, float* __restrict__ out) {
    int bid = blockIdx.x;
    int b = bid & 7;
    int blk = bid >> 3;                 // 0..1535
    int tid = threadIdx.x;
    int e = blk * 256 + tid;            // edge within batch, (n*K + k) flattened
    int n = e / K_;
    int k = e - n * K_;

    __shared__ float sWq[NEDGE][8];
    __shared__ float sR[K_ * NEDGE];    // 768 floats

    if (tid < NEDGE * 8) {
        int o = tid >> 3, f = tid & 7;
        sWq[o][f] = (f < 7) ? Wfull[o * FANIN + 16 + f] : 0.0f;
    }
    const float* rp = rinv + (size_t)b * K_ * NEDGE;
    for (int i = tid; i < K_ * NEDGE; i += 256) sR[i] = rp[i];
    __syncthreads();

    size_t bbase = (size_t)b * N_;
    size_t node = bbase + n;
    int j = E[node * K_ + k];

    const float4* fnp = (const float4*)(F + node * 12);
    float4 a0 = fnp[0], a1 = fnp[1], a2 = fnp[2];

    float h[NEDGE];
    compute_edge(a0, a1, a2, F, T, sWq, bbase, n, j, h);

    const float* rk = &sR[k * NEDGE];
    size_t base = ((size_t)bbase * K_ + (size_t)e) * 16;
    float4* op = (float4*)(out + base);
    op[0] = make_float4(h[0]*rk[0],   h[1]*rk[1],   h[2]*rk[2],   h[3]*rk[3]);
    op[1] = make_float4(h[4]*rk[4],   h[5]*rk[5],   h[6]*rk[6],   h[7]*rk[7]);
    op[2] = make_float4(h[8]*rk[8],   h[9]*rk[9],   h[10]*rk[10], h[11]*rk[11]);
    op[3] = make_float4(h[12]*rk[12], h[13]*rk[13], h[14]*rk[14], h[15]*rk[15]);
}

// ---------------- launch ----------------
extern "C" void kernel_launch(void* const* d_in, const int* in_sizes, int n_in,
                              void* d_out, int out_size, void* d_ws, size_t ws_size,
                              hipStream_t stream) {
    const float* X    = (const float*)d_in[0];   // p (B,N,3)
    const int*   E    = (const int*)d_in[1];     // e_idx (B,N,K)
    // d_in[2] = mask (unused by reference)
    const float* tfrq = (const float*)d_in[3];   // (8,)
    const float* ts   = (const float*)d_in[4];   // scalar
    const float* W    = (const float*)d_in[5];   // (16,23)
    const float* bias = (const float*)d_in[6];   // (16,)
    float* out = (float*)d_out;

    float* F = (float*)d_ws;                                   // 8*8192*12 f32 = 3.15 MB
    unsigned short* T = (unsigned short*)(F + (size_t)B_ * N_ * 12);  // 16383*16 bf16 = 524 KB
    float* acc  = (float*)(T + (size_t)DRANGE * 16);           // 6144 f32
    float* rinv = acc + B_ * K_ * NEDGE;                       // 6144 f32

    hipMemsetAsync(acc, 0, (size_t)B_ * K_ * NEDGE * sizeof(float), stream);

    build_table<<<(DRANGE + 255) / 256, 256, 0, stream>>>(tfrq, ts, W, bias, T);
    compute_F<<<(B_ * N_ + 255) / 256, 256, 0, stream>>>(X, F);

    int gridA = 8 * 4 * (N_ / 256);     // b in low 3 bits, then kq, then chunk
    ssq_pass<<<gridA, 256, 0, stream>>>(E, F, T, W, acc);

    inv_kernel<<<(B_ * K_ * NEDGE + 255) / 256, 256, 0, stream>>>(acc, rinv);

    int gridB = 8 * (N_ * K_ / 256);    // b in low 3 bits, then 1536 edge-chunks
    write_pass<<<gridB, 256, 0, stream>>>(E, F, T, W, rinv, out);
}

// Round 5
// 180.551 us; speedup vs baseline: 1.5968x; 1.1345x over previous
//
#include <hip/hip_runtime.h>
#include <math.h>

// Problem constants (from reference)
constexpr int B_ = 8;
constexpr int N_ = 8192;
constexpr int K_ = 48;
constexpr int NFREQ = 8;    // NUM_POS/2
constexpr int NEDGE = 16;
constexpr int FANIN = 23;   // NUM_POS + 7
constexpr float EPSF = 1e-12f;
constexpr int DRANGE = 2 * N_ - 1;  // 16383 possible d = j-n values, offset N_-1

// ---------------- helpers ----------------
struct F3 { float x, y, z; };
__device__ inline F3 f3(float a, float b, float c) { F3 r{a,b,c}; return r; }
__device__ inline F3 sub3(F3 a, F3 b) { return f3(a.x-b.x, a.y-b.y, a.z-b.z); }
__device__ inline F3 cross3(F3 a, F3 b) {
    return f3(a.y*b.z - a.z*b.y, a.z*b.x - a.x*b.z, a.x*b.y - a.y*b.x);
}
__device__ inline F3 norm3(F3 a) {
    float n = sqrtf(a.x*a.x + a.y*a.y + a.z*a.z);
    float inv = 1.0f / fmaxf(n, EPSF);
    return f3(a.x*inv, a.y*inv, a.z*inv);
}
__device__ inline float signf0(float x) {
    return (x > 0.0f) ? 1.0f : ((x < 0.0f) ? -1.0f : 0.0f);
}
__device__ inline unsigned int bf16rne(float x) {
    unsigned int u = __float_as_uint(x);
    return (u + 0x7fffu + ((u >> 16) & 1u)) >> 16;
}
// unpack 8 bf16 (one uint4) -> 8 floats
__device__ inline void unpack8(uint4 v, float* f) {
    f[0] = __uint_as_float(v.x << 16); f[1] = __uint_as_float(v.x & 0xffff0000u);
    f[2] = __uint_as_float(v.y << 16); f[3] = __uint_as_float(v.y & 0xffff0000u);
    f[4] = __uint_as_float(v.z << 16); f[5] = __uint_as_float(v.z & 0xffff0000u);
    f[6] = __uint_as_float(v.w << 16); f[7] = __uint_as_float(v.w & 0xffff0000u);
}

// ---------------- kernel 1: positional-encoding table (bf16, 32B rows) ----------------
__global__ void build_table(const float* __restrict__ tfrq, const float* __restrict__ ts,
                            const float* __restrict__ W, const float* __restrict__ bias,
                            unsigned short* __restrict__ T) {
    int idx = blockIdx.x * blockDim.x + threadIdx.x;
    if (idx >= DRANGE) return;
    float d = (float)(idx - (N_ - 1));
    float h[NEDGE];
    #pragma unroll
    for (int o = 0; o < NEDGE; o++) h[o] = bias[o];
    float tscale = ts[0];
    for (int f = 0; f < NFREQ; f++) {
        float s, c;
        sincosf(d * (tfrq[f] * tscale), &s, &c);
        #pragma unroll
        for (int o = 0; o < NEDGE; o++)
            h[o] = fmaf(s, W[o * FANIN + f], fmaf(c, W[o * FANIN + NFREQ + f], h[o]));
    }
    uint4 r0, r1;
    r0.x = bf16rne(h[0])  | (bf16rne(h[1])  << 16);
    r0.y = bf16rne(h[2])  | (bf16rne(h[3])  << 16);
    r0.z = bf16rne(h[4])  | (bf16rne(h[5])  << 16);
    r0.w = bf16rne(h[6])  | (bf16rne(h[7])  << 16);
    r1.x = bf16rne(h[8])  | (bf16rne(h[9])  << 16);
    r1.y = bf16rne(h[10]) | (bf16rne(h[11]) << 16);
    r1.z = bf16rne(h[12]) | (bf16rne(h[13]) << 16);
    r1.w = bf16rne(h[14]) | (bf16rne(h[15]) << 16);
    uint4* Tp = (uint4*)(T + (size_t)idx * 16);
    Tp[0] = r0; Tp[1] = r1;
}

// ---------------- kernel 2: per-node frame (12 floats packed, 64B stride) ----------------
// row0: X.xyz, o1.x ; row1: o1.yz, n2.xy ; row2: n2.z, c.xyz ; row3: pad
// 64B stride => each frame row set sits in ONE cache line (gather = 1 unique line)
__global__ void compute_F(const float* __restrict__ X, float* __restrict__ F) {
    int idx = blockIdx.x * blockDim.x + threadIdx.x;
    if (idx >= B_ * N_) return;
    int n = idx & (N_ - 1);
    const float* Xp = X + (size_t)idx * 3;
    float o[12];
    o[0] = Xp[0]; o[1] = Xp[1]; o[2] = Xp[2];
    #pragma unroll
    for (int i = 3; i < 12; i++) o[i] = 0.0f;
    if (n != 0 && n < N_ - 2) {
        F3 xm = f3(Xp[-3], Xp[-2], Xp[-1]);
        F3 x0 = f3(Xp[0], Xp[1], Xp[2]);
        F3 xp = f3(Xp[3], Xp[4], Xp[5]);
        F3 u2 = norm3(sub3(x0, xm));
        F3 u1 = norm3(sub3(xp, x0));
        F3 n2 = norm3(cross3(u2, u1));
        F3 o1 = norm3(sub3(u2, u1));
        F3 cc = cross3(o1, n2);
        o[3] = o1.x; o[4] = o1.y; o[5] = o1.z;
        o[6] = n2.x; o[7] = n2.y; o[8] = n2.z;
        o[9] = cc.x; o[10] = cc.y; o[11] = cc.z;
    }
    float4* Fp = (float4*)(F + (size_t)idx * 16);
    Fp[0] = make_float4(o[0], o[1], o[2], o[3]);
    Fp[1] = make_float4(o[4], o[5], o[6], o[7]);
    Fp[2] = make_float4(o[8], o[9], o[10], o[11]);
}

// ---------------- core per-edge computation ----------------
__device__ inline void compute_edge(float4 a0, float4 a1, float4 a2,
                                    const float* __restrict__ F,
                                    const unsigned short* __restrict__ T,
                                    const float (*sWq)[8],
                                    size_t bbase, int n, int j,
                                    float* __restrict__ h) {
    const float4* fjp = (const float4*)(F + (bbase + (size_t)j) * 16);
    float4 b0 = fjp[0], b1 = fjp[1], b2 = fjp[2];
    const uint4* tp = (const uint4*)(T + (size_t)(j - n + (N_ - 1)) * 16);
    uint4 t0 = tp[0], t1 = tp[1];
    float tv[16];
    unpack8(t0, tv);
    unpack8(t1, tv + 8);

    // frame: X=(r0.x,r0.y,r0.z) o1=(r0.w,r1.x,r1.y) n2=(r1.z,r1.w,r2.x) c=(r2.y,r2.z,r2.w)
    float A1x = a0.w, A1y = a1.x, A1z = a1.y;
    float A2x = a1.z, A2y = a1.w, A2z = a2.x;
    float A3x = a2.y, A3y = a2.z, A3z = a2.w;
    float B1x = b0.w, B1y = b1.x, B1z = b1.y;
    float B2x = b1.z, B2y = b1.w, B2z = b2.x;
    float B3x = b2.y, B3y = b2.z, B3z = b2.w;

    // dU = l2norm(Of @ dX): rows of Of are A1,A2,A3
    float dX0 = b0.x - a0.x, dX1 = b0.y - a0.y, dX2 = b0.z - a0.z;
    float v0 = A1x*dX0 + A1y*dX1 + A1z*dX2;
    float v1 = A2x*dX0 + A2y*dX1 + A2z*dX2;
    float v2 = A3x*dX0 + A3y*dX1 + A3z*dX2;
    float vinv = 1.0f / fmaxf(sqrtf(v0*v0 + v1*v1 + v2*v2), EPSF);
    float dU0 = v0*vinv, dU1 = v1*vinv, dU2 = v2*vinv;

    // R[i][l] = A1[i]B1[l] + A2[i]B2[l] + A3[i]B3[l]
    float R00 = A1x*B1x + A2x*B2x + A3x*B3x;
    float R11 = A1y*B1y + A2y*B2y + A3y*B3y;
    float R22 = A1z*B1z + A2z*B2z + A3z*B3z;
    float R21 = A1z*B1y + A2z*B2y + A3z*B3y;
    float R12 = A1y*B1z + A2y*B2z + A3y*B3z;
    float R02 = A1x*B1z + A2x*B2z + A3x*B3z;
    float R20 = A1z*B1x + A2z*B2x + A3z*B3x;
    float R10 = A1y*B1x + A2y*B2x + A3y*B3x;
    float R01 = A1x*B1y + A2x*B2y + A3x*B3y;

    float mg0 = 0.5f * sqrtf(fabsf(1.0f + R00 - R11 - R22) + EPSF);
    float mg1 = 0.5f * sqrtf(fabsf(1.0f - R00 + R11 - R22) + EPSF);
    float mg2 = 0.5f * sqrtf(fabsf(1.0f - R00 - R11 + R22) + EPSF);
    float qx = signf0(R21 - R12) * mg0;
    float qy = signf0(R02 - R20) * mg1;
    float qz = signf0(R10 - R01) * mg2;
    float qw = 0.5f * sqrtf(fmaxf(1.0f + R00 + R11 + R22, 0.0f) + EPSF);
    float qinv = 1.0f / fmaxf(sqrtf(qx*qx + qy*qy + qz*qz + qw*qw), EPSF);
    qx *= qinv; qy *= qinv; qz *= qinv; qw *= qinv;

    float q[7] = {dU0, dU1, dU2, qx, qy, qz, qw};
    #pragma unroll
    for (int o = 0; o < NEDGE; o++) {
        float a = tv[o];
        #pragma unroll
        for (int f = 0; f < 7; f++) a = fmaf(q[f], sWq[o][f], a);
        h[o] = a;
    }
}

// ---------------- single edge pass: unnormalized write + ssq reduce ----------------
// block = fixed (b,k), 256 consecutive n. grid = 8b x 48k x 32chunks = 12288 blocks.
__launch_bounds__(256)
__global__ void edge_pass(const int* __restrict__ E, const float* __restrict__ F,
                          const unsigned short* __restrict__ T, const float* __restrict__ Wfull,
                          float* __restrict__ acc, float* __restrict__ out) {
    int bid = blockIdx.x;
    int b = bid & 7;
    int r = bid >> 3;
    int k = r % K_;
    int chunk = r / K_;
    int tid = threadIdx.x;
    int n = chunk * 256 + tid;
    int lane = tid & 63, wid = tid >> 6;

    __shared__ float sWq[NEDGE][8];
    __shared__ float sAcc[4][NEDGE];

    if (tid < NEDGE * 8) {
        int o = tid >> 3, f = tid & 7;
        sWq[o][f] = (f < 7) ? Wfull[o * FANIN + 16 + f] : 0.0f;
    }
    __syncthreads();

    size_t bbase = (size_t)b * N_;
    size_t node = bbase + n;
    int j = E[node * K_ + k];

    const float4* fnp = (const float4*)(F + node * 16);
    float4 a0 = fnp[0], a1 = fnp[1], a2 = fnp[2];

    float h[NEDGE];
    compute_edge(a0, a1, a2, F, T, sWq, bbase, n, j, h);

    // unnormalized store (each edge = one 64B line)
    size_t base = (node * K_ + k) * 16;
    float4* op = (float4*)(out + base);
    op[0] = make_float4(h[0],  h[1],  h[2],  h[3]);
    op[1] = make_float4(h[4],  h[5],  h[6],  h[7]);
    op[2] = make_float4(h[8],  h[9],  h[10], h[11]);
    op[3] = make_float4(h[12], h[13], h[14], h[15]);

    // ssq reduce over n (lane axis): one butterfly per wave
    #pragma unroll
    for (int o = 0; o < NEDGE; o++) {
        float v = h[o] * h[o];
        #pragma unroll
        for (int m = 1; m < 64; m <<= 1) v += __shfl_xor(v, m, 64);
        if (lane == 0) sAcc[wid][o] = v;
    }
    __syncthreads();
    if (tid < NEDGE) {
        float t = sAcc[0][tid] + sAcc[1][tid] + sAcc[2][tid] + sAcc[3][tid];
        atomicAdd(&acc[((size_t)b * K_ + k) * NEDGE + tid], t);
    }
}

// ---------------- reciprocal norms ----------------
__global__ void inv_kernel(const float* __restrict__ acc, float* __restrict__ rinv) {
    int i = blockIdx.x * blockDim.x + threadIdx.x;
    if (i >= B_ * K_ * NEDGE) return;
    rinv[i] = 1.0f / fmaxf(sqrtf(acc[i]), EPSF);
}

// ---------------- rescale pass (streaming RMW, L3-resident re-read) ----------------
__launch_bounds__(256)
__global__ void scale_kernel(float* __restrict__ out, const float* __restrict__ rinv) {
    size_t idx = (size_t)blockIdx.x * blockDim.x + threadIdx.x;  // float4 index
    constexpr size_t TOTAL4 = (size_t)B_ * N_ * K_ * 4;
    if (idx >= TOTAL4) return;
    size_t e0 = idx * 4;
    unsigned int o0 = (unsigned int)(e0 & 15);
    unsigned int key = (unsigned int)(e0 >> 4);       // (b*N+n)*K + k
    unsigned int k = key % (unsigned int)K_;
    unsigned int b = key / (unsigned int)(N_ * K_);
    const float* rp = rinv + ((size_t)b * K_ + k) * 16 + o0;
    float4 vv = *reinterpret_cast<float4*>(out + e0);
    vv.x *= rp[0]; vv.y *= rp[1]; vv.z *= rp[2]; vv.w *= rp[3];
    *reinterpret_cast<float4*>(out + e0) = vv;
}

// ---------------- launch ----------------
extern "C" void kernel_launch(void* const* d_in, const int* in_sizes, int n_in,
                              void* d_out, int out_size, void* d_ws, size_t ws_size,
                              hipStream_t stream) {
    const float* X    = (const float*)d_in[0];   // p (B,N,3)
    const int*   E    = (const int*)d_in[1];     // e_idx (B,N,K)
    // d_in[2] = mask (unused by reference)
    const float* tfrq = (const float*)d_in[3];   // (8,)
    const float* ts   = (const float*)d_in[4];   // scalar
    const float* W    = (const float*)d_in[5];   // (16,23)
    const float* bias = (const float*)d_in[6];   // (16,)
    float* out = (float*)d_out;

    float* F = (float*)d_ws;                                          // 8*8192*16 f32 = 4.19 MB
    unsigned short* T = (unsigned short*)(F + (size_t)B_ * N_ * 16);  // 16383*16 bf16 = 524 KB
    float* acc  = (float*)(T + (size_t)DRANGE * 16);                  // 6144 f32
    float* rinv = acc + B_ * K_ * NEDGE;                              // 6144 f32

    hipMemsetAsync(acc, 0, (size_t)B_ * K_ * NEDGE * sizeof(float), stream);

    build_table<<<(DRANGE + 255) / 256, 256, 0, stream>>>(tfrq, ts, W, bias, T);
    compute_F<<<(B_ * N_ + 255) / 256, 256, 0, stream>>>(X, F);

    int grid = 8 * K_ * (N_ / 256);   // 12288 blocks, b in low 3 bits
    edge_pass<<<grid, 256, 0, stream>>>(E, F, T, W, acc, out);

    inv_kernel<<<(B_ * K_ * NEDGE + 255) / 256, 256, 0, stream>>>(acc, rinv);

    constexpr size_t TOTAL4 = (size_t)B_ * N_ * K_ * 4;
    scale_kernel<<<(TOTAL4 + 255) / 256, 256, 0, stream>>>(out, rinv);
}